// Round 8
// baseline (206.859 us; speedup 1.0000x reference)
//
#include <hip/hip_runtime.h>

// GPT-2 attention block, MI355X/gfx950.
// cvt(x)->bf16 | transpose(w)->bf16 [N,K] | QKV GEMM 128^2/8-wave/BK64
// 2-phase + XCD-chunked swizzle (q*0.125, k, V TRANSPOSED [B,H,HD,S]) |
// flash attention v5 (QBLK=128, 32 q/wave, KV-dbuf 1-barrier/tile) | proj GEMM
#define Bn 2
#define Sn 2048
#define Dn 1024
#define Hn 16
#define HDn 64

typedef unsigned short u16;
typedef u16 u16x4 __attribute__((ext_vector_type(4)));
typedef u16 u16x8 __attribute__((ext_vector_type(8)));
typedef __bf16 bf16x8 __attribute__((ext_vector_type(8)));
typedef float f32x4 __attribute__((ext_vector_type(4)));

__device__ __forceinline__ u16 cvt1(float f) {
  __bf16 h = (__bf16)f;
  return __builtin_bit_cast(u16, h);
}

__device__ __forceinline__ f32x4 mfma16(u16x8 a, u16x8 b, f32x4 c) {
  return __builtin_amdgcn_mfma_f32_16x16x32_bf16(
      __builtin_bit_cast(bf16x8, a), __builtin_bit_cast(bf16x8, b), c, 0, 0, 0);
}

// XOR swizzle for 128B-stride LDS tiles.
__device__ __forceinline__ int xorv(int row) {
  return (row & 7) ^ ((row >> 3) & 7);
}
__device__ __forceinline__ int swzb(int row, int bytecol) {
  return row * 128 + (bytecol ^ (xorv(row) << 4));
}

// ---------------- fp32 -> bf16 elementwise (vectorized) ----------------
__global__ __launch_bounds__(256) void k_cvt(const float* __restrict__ in,
                                             u16* __restrict__ out, int n4) {
  int i = blockIdx.x * 256 + threadIdx.x;
  if (i < n4) {
    const float4 v = reinterpret_cast<const float4*>(in)[i];
    u16x4 o = {cvt1(v.x), cvt1(v.y), cvt1(v.z), cvt1(v.w)};
    reinterpret_cast<u16x4*>(out)[i] = o;
  }
}

// ---------------- fp32 [K,N] -> bf16 [N,K] tiled transpose ----------------
__global__ __launch_bounds__(256) void k_transpose(const float* __restrict__ in,
                                                   u16* __restrict__ out,
                                                   int K, int N) {
  __shared__ u16 tile[32][33];
  const int n0 = blockIdx.x * 32, k0 = blockIdx.y * 32;
  const int tx = threadIdx.x, ty = threadIdx.y;
#pragma unroll
  for (int r = 0; r < 4; ++r) {
    const int k = ty * 4 + r;
    tile[k][tx] = cvt1(in[(size_t)(k0 + k) * N + n0 + tx]);
  }
  __syncthreads();
#pragma unroll
  for (int r = 0; r < 4; ++r) {
    const int n = ty * 4 + r;
    out[(size_t)(n0 + n) * K + k0 + tx] = tile[tx][n];
  }
}

// ---------------- bf16 GEMM  C[M,N] = A[M,K] * Bt[N,K]^T ----------------
// 128x128, 8 waves, BK=64, swizzled LDS, 2-phase, XCD-chunked block swizzle:
// each XCD gets a contiguous chunk of m-rows (n fastest) -> A-panel (1MB)
// L2-resident per XCD instead of scattered round-robin.
__global__ __launch_bounds__(512) void k_gemm2(
    const u16* __restrict__ A, const u16* __restrict__ Bt, int K,
    const float* __restrict__ bias, u16* __restrict__ oq, u16* __restrict__ ok,
    u16* __restrict__ ov, float* __restrict__ of, int mode) {
  __shared__ __align__(16) u16 a_lds[2][8192];
  __shared__ __align__(16) u16 b_lds[2][8192];
  const int tid = threadIdx.x;
  const int lane = tid & 63, w = tid >> 6;
  const int wr = w >> 2, wc = w & 3;
  const int lm = lane & 15, lk = lane >> 4;
  // XCD-chunked swizzle (nwg divisible by 8 for both our grids -> bijective)
  const int nx = gridDim.x;
  int lin = blockIdx.y * nx + blockIdx.x;
  const int cpx = (nx * gridDim.y) >> 3;
  lin = (lin & 7) * cpx + (lin >> 3);
  const int m0 = (lin / nx) * 128, n0 = (lin % nx) * 128;
  const int NT = K >> 6;

  const int srow0 = tid >> 3;
  const int scb = (tid & 7) * 16;

  f32x4 acc[4][2] = {};

#define STAGE2(d, kt)                                                         \
  {                                                                           \
    _Pragma("unroll") for (int p = 0; p < 2; ++p) {                           \
      const int row = p * 64 + srow0;                                         \
      const int col = (scb ^ (xorv(row) << 4)) >> 1;                          \
      __builtin_amdgcn_global_load_lds(                                       \
          (const __attribute__((address_space(1))) void*)(A + (size_t)(m0 + row) * K + (kt) * 64 + col), \
          (__attribute__((address_space(3))) void*)(a_lds[d] + p * 4096 + tid * 8), \
          16, 0, 0);                                                          \
      __builtin_amdgcn_global_load_lds(                                       \
          (const __attribute__((address_space(1))) void*)(Bt + (size_t)(n0 + row) * K + (kt) * 64 + col), \
          (__attribute__((address_space(3))) void*)(b_lds[d] + p * 4096 + tid * 8), \
          16, 0, 0);                                                          \
    }                                                                         \
  }

  STAGE2(0, 0);
  __syncthreads();

  for (int t = 0; t < NT; ++t) {
    const int cur = t & 1;
    if (t + 1 < NT) STAGE2(cur ^ 1, t + 1);
    u16x8 av[4][2], bv[2][2];
#pragma unroll
    for (int m = 0; m < 4; ++m)
#pragma unroll
      for (int kk = 0; kk < 2; ++kk)
        av[m][kk] = *reinterpret_cast<const u16x8*>(
            (char*)a_lds[cur] + swzb(wr * 64 + m * 16 + lm, kk * 64 + lk * 16));
#pragma unroll
    for (int n = 0; n < 2; ++n)
#pragma unroll
      for (int kk = 0; kk < 2; ++kk)
        bv[n][kk] = *reinterpret_cast<const u16x8*>(
            (char*)b_lds[cur] + swzb(wc * 32 + n * 16 + lm, kk * 64 + lk * 16));
    __builtin_amdgcn_s_setprio(1);
#pragma unroll
    for (int kk = 0; kk < 2; ++kk)
#pragma unroll
      for (int m = 0; m < 4; ++m)
#pragma unroll
        for (int n = 0; n < 2; ++n)
          acc[m][n] = mfma16(av[m][kk], bv[n][kk], acc[m][n]);
    __builtin_amdgcn_s_setprio(0);
    __syncthreads();
  }
#undef STAGE2

#pragma unroll
  for (int m = 0; m < 4; ++m) {
#pragma unroll
    for (int n = 0; n < 2; ++n) {
      const int col = n0 + wc * 32 + n * 16 + lm;
      const float bb = bias[col];
      const int row0 = m0 + wr * 64 + m * 16 + lk * 4;
      if (mode == 0) {
        const int which = col >> 10;
        const int h = (col >> 6) & 15, hd = col & 63;
        const int b = row0 >> 11, s0 = row0 & 2047;
        if (which == 2) {  // V transposed: [B,H,HD,S]
          u16x4 pk;
#pragma unroll
          for (int j = 0; j < 4; ++j) pk[j] = cvt1(acc[m][n][j] + bb);
          *reinterpret_cast<u16x4*>(
              ov + ((size_t)(b * Hn + h) * HDn + hd) * Sn + s0) = pk;
        } else {
          u16* dst = which == 0 ? oq : ok;
          const float sc = which == 0 ? 0.125f : 1.0f;
#pragma unroll
          for (int j = 0; j < 4; ++j)
            dst[((size_t)(b * Hn + h) * Sn + s0 + j) * HDn + hd] =
                cvt1((acc[m][n][j] + bb) * sc);
        }
      } else {
#pragma unroll
        for (int j = 0; j < 4; ++j)
          of[(size_t)(row0 + j) * Dn + col] = acc[m][n][j] + bb;
      }
    }
  }
}

// ---------------- causal flash attention (v5) ----------------
// QBLK=128: 4 waves x 32 q-rows (two 16-row frags). KV tile 64, K and V^T
// double-buffered in LDS -> ONE barrier per tile. Swapped QK^T, lane-local
// softmax, defer-max, per-frag full-mask skip.
__global__ __launch_bounds__(256) void k_attn(const u16* __restrict__ qb,
                                              const u16* __restrict__ kb,
                                              const u16* __restrict__ vtb,
                                              u16* __restrict__ ob) {
  const int bx = blockIdx.x;
  const int qt = 15 - (bx >> 5);   // longest blocks first
  const int bh = bx & 31;
  const int h = bh & 15, b = bh >> 4;
  const int tid = threadIdx.x, lane = tid & 63, w = tid >> 6;
  const int lm = lane & 15, lk = lane >> 4;
  const int Q0 = qt * 128;
  const int q0 = Q0 + w * 32;      // wave's 32 rows; frag f: q0 + f*16
  const size_t head = (size_t)(b * Hn + h) * Sn * HDn;
  const u16* Q = qb + head;
  const u16* Kp = kb + head;
  const u16* Vt = vtb + head;      // [HD][S] within head

  __shared__ __align__(16) u16 k_lds[2][64 * 64];
  __shared__ __align__(16) u16 vt_lds[2][64 * 64];
  __shared__ __align__(16) u16 p_lds[4][32 * 64];
  char* myp = (char*)p_lds[w];

  const int sr = tid >> 2, scb = (tid & 3) * 16;
  const u16* Ksrc = Kp + (size_t)sr * HDn + scb;
  const u16* Vsrc = Vt + (size_t)sr * Sn + scb;

  u16x8 aq[2][2];
#pragma unroll
  for (int f = 0; f < 2; ++f)
#pragma unroll
    for (int c = 0; c < 2; ++c)
      aq[f][c] = *reinterpret_cast<const u16x8*>(
          Q + (size_t)(q0 + f * 16 + lm) * HDn + c * 32 + lk * 8);

  f32x4 o_acc[2][4] = {};
  float mrow[2] = {-1e30f, -1e30f}, lrow[2] = {0.f, 0.f};
  const float C = 1.44269504f;

  const int NT = (Q0 + 128) >> 6;  // >= 2
  u16x8 kreg[2], vreg[2];

  // prologue: tile 0 -> regs -> buf0; load tile 1 regs
  kreg[0] = *reinterpret_cast<const u16x8*>(Ksrc);
  kreg[1] = *reinterpret_cast<const u16x8*>(Ksrc + 8);
  vreg[0] = *reinterpret_cast<const u16x8*>(Vsrc);
  vreg[1] = *reinterpret_cast<const u16x8*>(Vsrc + 8);
  *reinterpret_cast<u16x8*>((char*)k_lds[0] + swzb(sr, scb * 2)) = kreg[0];
  *reinterpret_cast<u16x8*>((char*)k_lds[0] + swzb(sr, scb * 2 + 16)) = kreg[1];
  *reinterpret_cast<u16x8*>((char*)vt_lds[0] + swzb(sr, scb * 2)) = vreg[0];
  *reinterpret_cast<u16x8*>((char*)vt_lds[0] + swzb(sr, scb * 2 + 16)) = vreg[1];
  {
    const u16* kn = Ksrc + (size_t)64 * HDn;
    const u16* vn = Vsrc + 64;
    kreg[0] = *reinterpret_cast<const u16x8*>(kn);
    kreg[1] = *reinterpret_cast<const u16x8*>(kn + 8);
    vreg[0] = *reinterpret_cast<const u16x8*>(vn);
    vreg[1] = *reinterpret_cast<const u16x8*>(vn + 8);
  }
  __syncthreads();

  for (int t = 0; t < NT; ++t) {
    const int cur = t & 1;
    const int j0 = t * 64;
    if (t + 1 < NT) {  // write next tile (regs) to other buffer
      *reinterpret_cast<u16x8*>((char*)k_lds[cur ^ 1] + swzb(sr, scb * 2)) = kreg[0];
      *reinterpret_cast<u16x8*>((char*)k_lds[cur ^ 1] + swzb(sr, scb * 2 + 16)) = kreg[1];
      *reinterpret_cast<u16x8*>((char*)vt_lds[cur ^ 1] + swzb(sr, scb * 2)) = vreg[0];
      *reinterpret_cast<u16x8*>((char*)vt_lds[cur ^ 1] + swzb(sr, scb * 2 + 16)) = vreg[1];
      if (t + 2 < NT) {  // issue loads for tile t+2 (land during next iter)
        const u16* kn = Ksrc + (size_t)(j0 + 128) * HDn;
        const u16* vn = Vsrc + (j0 + 128);
        kreg[0] = *reinterpret_cast<const u16x8*>(kn);
        kreg[1] = *reinterpret_cast<const u16x8*>(kn + 8);
        vreg[0] = *reinterpret_cast<const u16x8*>(vn);
        vreg[1] = *reinterpret_cast<const u16x8*>(vn + 8);
      }
    }

    const bool act[2] = {j0 <= q0 + 15, j0 <= q0 + 31};

    // ---- QK^T (swapped): lane holds S[q0+f*16+lm][j0+kc*16+lk*4+jj]
    f32x4 s[2][4];
    __builtin_amdgcn_s_setprio(1);
#pragma unroll
    for (int kc = 0; kc < 4; ++kc) {
      const u16x8 kf0 = *reinterpret_cast<const u16x8*>(
          (char*)k_lds[cur] + swzb(kc * 16 + lm, lk * 16));
      const u16x8 kf1 = *reinterpret_cast<const u16x8*>(
          (char*)k_lds[cur] + swzb(kc * 16 + lm, 64 + lk * 16));
#pragma unroll
      for (int f = 0; f < 2; ++f) {
        if (!act[f]) continue;
        f32x4 z = {};
        z = mfma16(kf0, aq[f][0], z);
        s[f][kc] = mfma16(kf1, aq[f][1], z);
      }
    }
    __builtin_amdgcn_s_setprio(0);

#pragma unroll
    for (int f = 0; f < 2; ++f) {
      if (!act[f]) continue;
      const int q0f = q0 + f * 16;
      if (j0 + 63 > q0f) {  // causal mask (diagonal region only)
#pragma unroll
        for (int kc = 0; kc < 4; ++kc)
#pragma unroll
          for (int jj = 0; jj < 4; ++jj)
            if (j0 + kc * 16 + lk * 4 + jj > q0f + lm) s[f][kc][jj] = -1e30f;
      }
      // ---- online softmax (lane-local row), defer-max THR=8 ----
      float vmax = -1e30f;
#pragma unroll
      for (int kc = 0; kc < 4; ++kc)
#pragma unroll
        for (int jj = 0; jj < 4; ++jj) vmax = fmaxf(vmax, s[f][kc][jj]);
      vmax = fmaxf(vmax, __shfl_xor(vmax, 16, 64));
      vmax = fmaxf(vmax, __shfl_xor(vmax, 32, 64));
      if (!__all(vmax - mrow[f] <= 8.0f)) {
        const float mnew = fmaxf(mrow[f], vmax);
        const float alpha = exp2f((mrow[f] - mnew) * C);
        mrow[f] = mnew;
        lrow[f] *= alpha;
        float a4[4];
#pragma unroll
        for (int jj = 0; jj < 4; ++jj) a4[jj] = __shfl(alpha, lk * 4 + jj, 64);
#pragma unroll
        for (int tt = 0; tt < 4; ++tt)
#pragma unroll
          for (int jj = 0; jj < 4; ++jj) o_acc[f][tt][jj] *= a4[jj];
      }
      const float mc = mrow[f] * C;
      float psum = 0.f;
#pragma unroll
      for (int kc = 0; kc < 4; ++kc) {
        u16x4 pk;
#pragma unroll
        for (int jj = 0; jj < 4; ++jj) {
          const float p = exp2f(s[f][kc][jj] * C - mc);
          psum += p;
          pk[jj] = cvt1(p);
        }
        *reinterpret_cast<u16x4*>(myp + swzb(f * 16 + lm, kc * 32 + lk * 8)) = pk;
      }
      psum += __shfl_xor(psum, 16, 64);
      psum += __shfl_xor(psum, 32, 64);
      lrow[f] += psum;
    }

    // ---- PV: O[q][d] += P * V  (vf shared across frags)
    __builtin_amdgcn_s_setprio(1);
#pragma unroll
    for (int kt = 0; kt < 2; ++kt) {
      u16x8 vf[4];
#pragma unroll
      for (int tt = 0; tt < 4; ++tt)
        vf[tt] = *reinterpret_cast<const u16x8*>(
            (char*)vt_lds[cur] + swzb(tt * 16 + lm, kt * 64 + lk * 16));
#pragma unroll
      for (int f = 0; f < 2; ++f) {
        if (!act[f]) continue;
        const u16x8 pa = *reinterpret_cast<const u16x8*>(
            myp + swzb(f * 16 + lm, kt * 64 + lk * 16));
#pragma unroll
        for (int tt = 0; tt < 4; ++tt)
          o_acc[f][tt] = mfma16(pa, vf[tt], o_acc[f][tt]);
      }
    }
    __builtin_amdgcn_s_setprio(0);
    __syncthreads();  // single barrier per tile
  }

#pragma unroll
  for (int f = 0; f < 2; ++f) {
    float l4[4];
#pragma unroll
    for (int jj = 0; jj < 4; ++jj) l4[jj] = __shfl(lrow[f], lk * 4 + jj, 64);
#pragma unroll
    for (int tt = 0; tt < 4; ++tt) {
#pragma unroll
      for (int jj = 0; jj < 4; ++jj) {
        const int rowg = q0 + f * 16 + lk * 4 + jj;
        const float val = o_acc[f][tt][jj] / l4[jj];
        ob[((size_t)(b * Sn + rowg)) * Dn + h * HDn + tt * 16 + lm] = cvt1(val);
      }
    }
  }
}

extern "C" void kernel_launch(void* const* d_in, const int* in_sizes, int n_in,
                              void* d_out, int out_size, void* d_ws, size_t ws_size,
                              hipStream_t stream) {
  const float* x = (const float*)d_in[0];
  const float* w_attn = (const float*)d_in[1];
  const float* b_attn = (const float*)d_in[2];
  const float* w_proj = (const float*)d_in[3];
  const float* b_proj = (const float*)d_in[4];
  float* out = (float*)d_out;

  u16* ws = (u16*)d_ws;
  u16* xb = ws;                                  // [4096,1024]
  u16* wat = xb + (size_t)4096 * 1024;           // [3072,1024]
  u16* wpt = wat + (size_t)3072 * 1024;          // [1024,1024]
  u16* qb = wpt + (size_t)1024 * 1024;           // [B,H,S,HD]
  u16* kb = qb + (size_t)Bn * Hn * Sn * HDn;     // [B,H,S,HD]
  u16* vtb = kb + (size_t)Bn * Hn * Sn * HDn;    // [B,H,HD,S] (transposed!)
  u16* ao = vtb + (size_t)Bn * Hn * Sn * HDn;    // [4096,1024]

  k_cvt<<<4096, 256, 0, stream>>>(x, xb, 1048576);
  k_transpose<<<dim3(3072 / 32, 1024 / 32), dim3(32, 8), 0, stream>>>(w_attn, wat, 1024, 3072);
  k_transpose<<<dim3(1024 / 32, 1024 / 32), dim3(32, 8), 0, stream>>>(w_proj, wpt, 1024, 1024);
  k_gemm2<<<dim3(3072 / 128, 4096 / 128), 512, 0, stream>>>(xb, wat, 1024, b_attn, qb, kb, vtb, nullptr, 0);
  k_attn<<<Bn * Hn * (Sn / 128), 256, 0, stream>>>(qb, kb, vtb, ao);
  k_gemm2<<<dim3(1024 / 128, 4096 / 128), 512, 0, stream>>>(ao, wpt, 1024, b_proj, nullptr, nullptr, nullptr, out, 1);
}

// Round 9
// 186.126 us; speedup vs baseline: 1.1114x; 1.1114x over previous
//
#include <hip/hip_runtime.h>

// GPT-2 attention block, MI355X/gfx950.
// cvt(x)->bf16 | transpose(w)->bf16 [N,K] | QKV GEMM 128^2/8-wave/BK64
// 2-phase, XCD chunking with m-fastest grouping (A-chunk L2-resident) |
// flash attention v4 (QBLK=64, swapped QK^T, vector V^T staging) | proj GEMM
#define Bn 2
#define Sn 2048
#define Dn 1024
#define Hn 16
#define HDn 64

typedef unsigned short u16;
typedef u16 u16x4 __attribute__((ext_vector_type(4)));
typedef u16 u16x8 __attribute__((ext_vector_type(8)));
typedef __bf16 bf16x8 __attribute__((ext_vector_type(8)));
typedef float f32x4 __attribute__((ext_vector_type(4)));

__device__ __forceinline__ u16 cvt1(float f) {
  __bf16 h = (__bf16)f;
  return __builtin_bit_cast(u16, h);
}

__device__ __forceinline__ f32x4 mfma16(u16x8 a, u16x8 b, f32x4 c) {
  return __builtin_amdgcn_mfma_f32_16x16x32_bf16(
      __builtin_bit_cast(bf16x8, a), __builtin_bit_cast(bf16x8, b), c, 0, 0, 0);
}

// XOR swizzle for 128B-stride LDS tiles.
__device__ __forceinline__ int xorv(int row) {
  return (row & 7) ^ ((row >> 3) & 7);
}
__device__ __forceinline__ int swzb(int row, int bytecol) {
  return row * 128 + (bytecol ^ (xorv(row) << 4));
}

// ---------------- fp32 -> bf16 elementwise (vectorized) ----------------
__global__ __launch_bounds__(256) void k_cvt(const float* __restrict__ in,
                                             u16* __restrict__ out, int n4) {
  int i = blockIdx.x * 256 + threadIdx.x;
  if (i < n4) {
    const float4 v = reinterpret_cast<const float4*>(in)[i];
    u16x4 o = {cvt1(v.x), cvt1(v.y), cvt1(v.z), cvt1(v.w)};
    reinterpret_cast<u16x4*>(out)[i] = o;
  }
}

// ---------------- fp32 [K,N] -> bf16 [N,K] tiled transpose ----------------
__global__ __launch_bounds__(256) void k_transpose(const float* __restrict__ in,
                                                   u16* __restrict__ out,
                                                   int K, int N) {
  __shared__ u16 tile[32][33];
  const int n0 = blockIdx.x * 32, k0 = blockIdx.y * 32;
  const int tx = threadIdx.x, ty = threadIdx.y;
#pragma unroll
  for (int r = 0; r < 4; ++r) {
    const int k = ty * 4 + r;
    tile[k][tx] = cvt1(in[(size_t)(k0 + k) * N + n0 + tx]);
  }
  __syncthreads();
#pragma unroll
  for (int r = 0; r < 4; ++r) {
    const int n = ty * 4 + r;
    out[(size_t)(n0 + n) * K + k0 + tx] = tile[tx][n];
  }
}

// ---------------- bf16 GEMM  C[M,N] = A[M,K] * Bt[N,K]^T ----------------
// 128x128, 8 waves, BK=64, swizzled LDS, 2-phase. Block order: XCD chunk
// (lin&7) owns 4 consecutive m-blocks; within chunk m varies FASTEST
// (4-group) so the 1MB A-chunk stays L2-resident while B streams once.
template <int MODE>
__global__ __launch_bounds__(512) void k_gemm2(
    const u16* __restrict__ A, const u16* __restrict__ Bt, int K,
    const float* __restrict__ bias, u16* __restrict__ oq, u16* __restrict__ ok,
    u16* __restrict__ ov, float* __restrict__ of) {
  __shared__ __align__(16) u16 a_lds[2][8192];
  __shared__ __align__(16) u16 b_lds[2][8192];
  const int tid = threadIdx.x;
  const int lane = tid & 63, w = tid >> 6;
  const int wr = w >> 2, wc = w & 3;
  const int lm = lane & 15, lk = lane >> 4;
  const int nx = gridDim.x;
  const int lin = blockIdx.y * nx + blockIdx.x;
  // XCD = lin%8 (round-robin dispatch). Same-XCD blocks: m-fastest 4-group.
  const int m0 = ((lin & 7) * 4 + ((lin >> 3) & 3)) * 128;
  const int n0 = ((lin >> 3) >> 2) * 128;
  const int NT = K >> 6;

  const int srow0 = tid >> 3;
  const int scb = (tid & 7) * 16;

  f32x4 acc[4][2] = {};

#define STAGE2(d, kt)                                                         \
  {                                                                           \
    _Pragma("unroll") for (int p = 0; p < 2; ++p) {                           \
      const int row = p * 64 + srow0;                                         \
      const int col = (scb ^ (xorv(row) << 4)) >> 1;                          \
      __builtin_amdgcn_global_load_lds(                                       \
          (const __attribute__((address_space(1))) void*)(A + (size_t)(m0 + row) * K + (kt) * 64 + col), \
          (__attribute__((address_space(3))) void*)(a_lds[d] + p * 4096 + tid * 8), \
          16, 0, 0);                                                          \
      __builtin_amdgcn_global_load_lds(                                       \
          (const __attribute__((address_space(1))) void*)(Bt + (size_t)(n0 + row) * K + (kt) * 64 + col), \
          (__attribute__((address_space(3))) void*)(b_lds[d] + p * 4096 + tid * 8), \
          16, 0, 0);                                                          \
    }                                                                         \
  }

  STAGE2(0, 0);
  __syncthreads();

  for (int t = 0; t < NT; ++t) {
    const int cur = t & 1;
    if (t + 1 < NT) STAGE2(cur ^ 1, t + 1);
    u16x8 av[4][2], bv[2][2];
#pragma unroll
    for (int m = 0; m < 4; ++m)
#pragma unroll
      for (int kk = 0; kk < 2; ++kk)
        av[m][kk] = *reinterpret_cast<const u16x8*>(
            (char*)a_lds[cur] + swzb(wr * 64 + m * 16 + lm, kk * 64 + lk * 16));
#pragma unroll
    for (int n = 0; n < 2; ++n)
#pragma unroll
      for (int kk = 0; kk < 2; ++kk)
        bv[n][kk] = *reinterpret_cast<const u16x8*>(
            (char*)b_lds[cur] + swzb(wc * 32 + n * 16 + lm, kk * 64 + lk * 16));
    __builtin_amdgcn_s_setprio(1);
#pragma unroll
    for (int kk = 0; kk < 2; ++kk)
#pragma unroll
      for (int m = 0; m < 4; ++m)
#pragma unroll
        for (int n = 0; n < 2; ++n)
          acc[m][n] = mfma16(av[m][kk], bv[n][kk], acc[m][n]);
    __builtin_amdgcn_s_setprio(0);
    __syncthreads();
  }
#undef STAGE2

#pragma unroll
  for (int m = 0; m < 4; ++m) {
#pragma unroll
    for (int n = 0; n < 2; ++n) {
      const int col = n0 + wc * 32 + n * 16 + lm;
      const float bb = bias[col];
      const int row0 = m0 + wr * 64 + m * 16 + lk * 4;
      if (MODE == 0) {
        const int which = col >> 10;
        const int h = (col >> 6) & 15, hd = col & 63;
        const int b = row0 >> 11, s0 = row0 & 2047;
        if (which == 2) {  // V transposed: [B,H,HD,S]
          u16x4 pk;
#pragma unroll
          for (int j = 0; j < 4; ++j) pk[j] = cvt1(acc[m][n][j] + bb);
          *reinterpret_cast<u16x4*>(
              ov + ((size_t)(b * Hn + h) * HDn + hd) * Sn + s0) = pk;
        } else {
          u16* dst = which == 0 ? oq : ok;
          const float sc = which == 0 ? 0.125f : 1.0f;
#pragma unroll
          for (int j = 0; j < 4; ++j)
            dst[((size_t)(b * Hn + h) * Sn + s0 + j) * HDn + hd] =
                cvt1((acc[m][n][j] + bb) * sc);
        }
      } else {
#pragma unroll
        for (int j = 0; j < 4; ++j)
          of[(size_t)(row0 + j) * Dn + col] = acc[m][n][j] + bb;
      }
    }
  }
}

// ---------------- causal flash attention (v4, known-good 54us) ----------
// QBLK=64, 4 waves x 16 q-rows. Swapped QK^T, lane-local softmax with
// defer-max, V pre-transposed in global -> vector b128 LDS staging.
__global__ __launch_bounds__(256) void k_attn(const u16* __restrict__ qb,
                                              const u16* __restrict__ kb,
                                              const u16* __restrict__ vtb,
                                              u16* __restrict__ ob) {
  const int bx = blockIdx.x;
  const int qt = 31 - (bx >> 5);   // longest blocks first
  const int bh = bx & 31;
  const int h = bh & 15, b = bh >> 4;
  const int tid = threadIdx.x, lane = tid & 63, w = tid >> 6;
  const int lm = lane & 15, lk = lane >> 4;
  const int Q0 = qt * 64;
  const int q0 = Q0 + w * 16;
  const size_t head = (size_t)(b * Hn + h) * Sn * HDn;
  const u16* Q = qb + head;
  const u16* Kp = kb + head;
  const u16* Vt = vtb + head;  // [HD][S] within head

  __shared__ __align__(16) u16 k_lds[64 * 64];
  __shared__ __align__(16) u16 vt_lds[64 * 64];
  __shared__ __align__(16) u16 p_lds[4][16 * 64];
  char* myp = (char*)p_lds[w];

  const int sr = tid >> 2, scb = (tid & 3) * 16;
  const u16* Ksrc = Kp + (size_t)sr * HDn + scb;
  const u16* Vsrc = Vt + (size_t)sr * Sn + scb;

  u16x8 aq[2];
#pragma unroll
  for (int c = 0; c < 2; ++c)
    aq[c] = *reinterpret_cast<const u16x8*>(Q + (size_t)(q0 + lm) * HDn + c * 32 + lk * 8);

  f32x4 o_acc[4] = {};
  float mrow = -1e30f, lrow = 0.f;
  const float C = 1.44269504f;

  const int nk = Q0 + 64;
  u16x8 kreg[2], vreg[2];
  kreg[0] = *reinterpret_cast<const u16x8*>(Ksrc);
  kreg[1] = *reinterpret_cast<const u16x8*>(Ksrc + 8);
  vreg[0] = *reinterpret_cast<const u16x8*>(Vsrc);
  vreg[1] = *reinterpret_cast<const u16x8*>(Vsrc + 8);

  for (int j0 = 0; j0 < nk; j0 += 64) {
    *reinterpret_cast<u16x8*>((char*)k_lds + swzb(sr, scb * 2)) = kreg[0];
    *reinterpret_cast<u16x8*>((char*)k_lds + swzb(sr, scb * 2 + 16)) = kreg[1];
    *reinterpret_cast<u16x8*>((char*)vt_lds + swzb(sr, scb * 2)) = vreg[0];
    *reinterpret_cast<u16x8*>((char*)vt_lds + swzb(sr, scb * 2 + 16)) = vreg[1];
    __syncthreads();
    if (j0 + 64 < nk) {
      const u16* kn = Ksrc + (size_t)(j0 + 64) * HDn;
      const u16* vn = Vsrc + (j0 + 64);
      kreg[0] = *reinterpret_cast<const u16x8*>(kn);
      kreg[1] = *reinterpret_cast<const u16x8*>(kn + 8);
      vreg[0] = *reinterpret_cast<const u16x8*>(vn);
      vreg[1] = *reinterpret_cast<const u16x8*>(vn + 8);
    }

    // ---- QK^T (swapped): lane holds S[q0+lm][j0+kc*16+lk*4+jj]
    f32x4 s[4];
    __builtin_amdgcn_s_setprio(1);
#pragma unroll
    for (int kc = 0; kc < 4; ++kc) {
      const u16x8 kf0 = *reinterpret_cast<const u16x8*>((char*)k_lds + swzb(kc * 16 + lm, lk * 16));
      const u16x8 kf1 = *reinterpret_cast<const u16x8*>((char*)k_lds + swzb(kc * 16 + lm, 64 + lk * 16));
      f32x4 z = {};
      z = mfma16(kf0, aq[0], z);
      s[kc] = mfma16(kf1, aq[1], z);
    }
    __builtin_amdgcn_s_setprio(0);
    if (j0 + 63 > q0) {
#pragma unroll
      for (int kc = 0; kc < 4; ++kc)
#pragma unroll
        for (int jj = 0; jj < 4; ++jj)
          if (j0 + kc * 16 + lk * 4 + jj > q0 + lm) s[kc][jj] = -1e30f;
    }

    // ---- online softmax (lane-local row), defer-max THR=8 ----
    float vmax = -1e30f;
#pragma unroll
    for (int kc = 0; kc < 4; ++kc)
#pragma unroll
      for (int jj = 0; jj < 4; ++jj) vmax = fmaxf(vmax, s[kc][jj]);
    vmax = fmaxf(vmax, __shfl_xor(vmax, 16, 64));
    vmax = fmaxf(vmax, __shfl_xor(vmax, 32, 64));
    if (!__all(vmax - mrow <= 8.0f)) {
      const float mnew = fmaxf(mrow, vmax);
      const float alpha = exp2f((mrow - mnew) * C);
      mrow = mnew;
      lrow *= alpha;
      float a4[4];
#pragma unroll
      for (int jj = 0; jj < 4; ++jj) a4[jj] = __shfl(alpha, lk * 4 + jj, 64);
#pragma unroll
      for (int t = 0; t < 4; ++t)
#pragma unroll
        for (int jj = 0; jj < 4; ++jj) o_acc[t][jj] *= a4[jj];
    }
    const float mc = mrow * C;
    float psum = 0.f;
#pragma unroll
    for (int kc = 0; kc < 4; ++kc) {
      u16x4 pk;
#pragma unroll
      for (int jj = 0; jj < 4; ++jj) {
        const float p = exp2f(s[kc][jj] * C - mc);
        psum += p;
        pk[jj] = cvt1(p);
      }
      *reinterpret_cast<u16x4*>(myp + swzb(lm, kc * 32 + lk * 8)) = pk;
    }
    psum += __shfl_xor(psum, 16, 64);
    psum += __shfl_xor(psum, 32, 64);
    lrow += psum;

    // ---- PV: O[q][d] += P * V
    __builtin_amdgcn_s_setprio(1);
#pragma unroll
    for (int kt = 0; kt < 2; ++kt) {
      const u16x8 pa = *reinterpret_cast<const u16x8*>(myp + swzb(lm, kt * 64 + lk * 16));
#pragma unroll
      for (int t = 0; t < 4; ++t) {
        const u16x8 vf = *reinterpret_cast<const u16x8*>((char*)vt_lds + swzb(t * 16 + lm, kt * 64 + lk * 16));
        o_acc[t] = mfma16(pa, vf, o_acc[t]);
      }
    }
    __builtin_amdgcn_s_setprio(0);
    __syncthreads();
  }

  float l4[4];
#pragma unroll
  for (int jj = 0; jj < 4; ++jj) l4[jj] = __shfl(lrow, lk * 4 + jj, 64);
#pragma unroll
  for (int t = 0; t < 4; ++t) {
#pragma unroll
    for (int jj = 0; jj < 4; ++jj) {
      const int rowg = q0 + lk * 4 + jj;
      const float val = o_acc[t][jj] / l4[jj];
      ob[((size_t)(b * Sn + rowg)) * Dn + h * HDn + t * 16 + lm] = cvt1(val);
    }
  }
}

extern "C" void kernel_launch(void* const* d_in, const int* in_sizes, int n_in,
                              void* d_out, int out_size, void* d_ws, size_t ws_size,
                              hipStream_t stream) {
  const float* x = (const float*)d_in[0];
  const float* w_attn = (const float*)d_in[1];
  const float* b_attn = (const float*)d_in[2];
  const float* w_proj = (const float*)d_in[3];
  const float* b_proj = (const float*)d_in[4];
  float* out = (float*)d_out;

  u16* ws = (u16*)d_ws;
  u16* xb = ws;                                  // [4096,1024]
  u16* wat = xb + (size_t)4096 * 1024;           // [3072,1024]
  u16* wpt = wat + (size_t)3072 * 1024;          // [1024,1024]
  u16* qb = wpt + (size_t)1024 * 1024;           // [B,H,S,HD]
  u16* kb = qb + (size_t)Bn * Hn * Sn * HDn;     // [B,H,S,HD]
  u16* vtb = kb + (size_t)Bn * Hn * Sn * HDn;    // [B,H,HD,S] (transposed!)
  u16* ao = vtb + (size_t)Bn * Hn * Sn * HDn;    // [4096,1024]

  k_cvt<<<4096, 256, 0, stream>>>(x, xb, 1048576);
  k_transpose<<<dim3(3072 / 32, 1024 / 32), dim3(32, 8), 0, stream>>>(w_attn, wat, 1024, 3072);
  k_transpose<<<dim3(1024 / 32, 1024 / 32), dim3(32, 8), 0, stream>>>(w_proj, wpt, 1024, 1024);
  k_gemm2<0><<<dim3(3072 / 128, 4096 / 128), 512, 0, stream>>>(xb, wat, 1024, b_attn, qb, kb, vtb, nullptr);
  k_attn<<<Bn * Hn * (Sn / 64), 256, 0, stream>>>(qb, kb, vtb, ao);
  k_gemm2<1><<<dim3(1024 / 128, 4096 / 128), 512, 0, stream>>>(ao, wpt, 1024, b_proj, nullptr, nullptr, nullptr, out);
}